// Round 7
// baseline (297.985 us; speedup 1.0000x reference)
//
#include <hip/hip_runtime.h>

#define NROW 512
#define NCOL 65536

static __device__ __forceinline__ float wave_sum(float x) {
  #pragma unroll
  for (int off = 32; off; off >>= 1) x += __shfl_down(x, off, 64);
  return x;
}

// Device-scope grid barrier (monotone phase counter). All 256 blocks
// co-resident (1 block/CU, 256 <= 256 CUs).
static __device__ __forceinline__ void gbar(int* cnt, int* phase) {
  __syncthreads();
  if (threadIdx.x == 0) {
    int ph = atomicAdd(phase, 0);                 // read phase BEFORE arriving
    __threadfence();                              // release prior writes
    if (atomicAdd(cnt, 1) == (int)gridDim.x - 1) {
      atomicExch(cnt, 0);
      __threadfence();
      atomicAdd(phase, 1);                        // release waiters
    } else {
      while (atomicAdd(phase, 0) == ph) { __builtin_amdgcn_s_sleep(8); }
    }
    __threadfence();                              // acquire
  }
  __syncthreads();
}

// ---- init: zero the barrier + accumulators (ws is poisoned) ---------------
__global__ void init_ws(float* __restrict__ eA, int* __restrict__ bar) {
  if (threadIdx.x < 8) eA[threadIdx.x] = 0.f;  // [0]=err1 [1]=err51 [2]=loss
  if (threadIdx.x < 2) bar[threadIdx.x] = 0;   // cnt, phase
}

// ---- one persistent kernel: 256 blocks x 1024 thr (1 block/CU) -------------
// Phase A: v1 = b/(colsum(E)/512+eps)        [block owns 256-col slab]
// Phase B: u1 = a/(E v1+eps) + loss partial  [block owns 2 rows]
// Phase C: t = colsum(E^T u1) (regs), err1
// decide -> out, or fallback iters 2..100 (same structure, gbar-synced)
__global__ __launch_bounds__(1024)
void sinkhorn_all(const float* __restrict__ M, float* __restrict__ out,
                  float* __restrict__ v, float* __restrict__ u,
                  float* __restrict__ eA, int* __restrict__ bar) {
  const int tid = threadIdx.x, bid = blockIdx.x;
  const float am = 1.0f / NROW, bm = 1.0f / NCOL, EPSV = 1e-16f;
  int* cnt = bar;
  int* phs = bar + 1;

  __shared__ float sU[NROW];
  __shared__ float sCol[16 * 256];
  __shared__ float sRedA[16], sRedB[16], sRedC[16], sRedD[16];
  __shared__ float sDecE, sDecL;

  const int chunk = tid & 63;          // 64 float4 chunks = 256 cols per block
  const int part  = tid >> 6;          // 16 waves x 32 rows each
  const int col0  = (bid << 8) + (chunk << 2);
  const int r0    = part << 5;
  const int row0  = bid << 1;

  // ---- Phase A: colsum(E) for this block's 256 cols -> v slice -------------
  {
    const float* Mp = M + (size_t)r0 * NCOL + col0;
    float4 cs = {0.f, 0.f, 0.f, 0.f};
    #pragma unroll 8
    for (int rr = 0; rr < 32; ++rr) {
      float4 m = *(const float4*)(Mp + (size_t)rr * NCOL);
      cs.x += __expf(-20.f * m.x);
      cs.y += __expf(-20.f * m.y);
      cs.z += __expf(-20.f * m.z);
      cs.w += __expf(-20.f * m.w);
    }
    *(float4*)(sCol + part * 256 + (chunk << 2)) = cs;
    __syncthreads();
    if (tid < 256) {
      float t = 0.f;
      #pragma unroll
      for (int p = 0; p < 16; ++p) t += sCol[p * 256 + tid];
      v[(bid << 8) + tid] = bm / (t * am + EPSV);
    }
  }
  gbar(cnt, phs);

  // ---- Phase B: row dots (u1) + fused loss partial -------------------------
  {
    const float4* M40 = (const float4*)M + (size_t)row0 * (NCOL / 4);
    const float4* M41 = M40 + (NCOL / 4);
    const float4* V4  = (const float4*)v;
    float ra = 0.f, rb = 0.f, sa = 0.f, sb = 0.f;
    #pragma unroll 4
    for (int it = 0; it < NCOL / 4 / 1024; ++it) {   // 16 iters
      const int c = (it << 10) + tid;
      float4 vv = V4[c];
      float4 m0 = M40[c], m1 = M41[c];
      float e;
      e = __expf(-20.f * m0.x); ra = fmaf(e, vv.x, ra); sa = fmaf(e * m0.x, vv.x, sa);
      e = __expf(-20.f * m0.y); ra = fmaf(e, vv.y, ra); sa = fmaf(e * m0.y, vv.y, sa);
      e = __expf(-20.f * m0.z); ra = fmaf(e, vv.z, ra); sa = fmaf(e * m0.z, vv.z, sa);
      e = __expf(-20.f * m0.w); ra = fmaf(e, vv.w, ra); sa = fmaf(e * m0.w, vv.w, sa);
      e = __expf(-20.f * m1.x); rb = fmaf(e, vv.x, rb); sb = fmaf(e * m1.x, vv.x, sb);
      e = __expf(-20.f * m1.y); rb = fmaf(e, vv.y, rb); sb = fmaf(e * m1.y, vv.y, sb);
      e = __expf(-20.f * m1.z); rb = fmaf(e, vv.z, rb); sb = fmaf(e * m1.z, vv.z, sb);
      e = __expf(-20.f * m1.w); rb = fmaf(e, vv.w, rb); sb = fmaf(e * m1.w, vv.w, sb);
    }
    ra = wave_sum(ra); rb = wave_sum(rb);
    sa = wave_sum(sa); sb = wave_sum(sb);
    if ((tid & 63) == 0) {
      sRedA[tid >> 6] = ra; sRedB[tid >> 6] = rb;
      sRedC[tid >> 6] = sa; sRedD[tid >> 6] = sb;
    }
    __syncthreads();
    if (tid == 0) {
      float rs0 = 0.f, rs1 = 0.f, ss0 = 0.f, ss1 = 0.f;
      #pragma unroll
      for (int w = 0; w < 16; ++w) {
        rs0 += sRedA[w]; rs1 += sRedB[w];
        ss0 += sRedC[w]; ss1 += sRedD[w];
      }
      float u0v = am / (rs0 + EPSV);
      float u1v = am / (rs1 + EPSV);
      u[row0] = u0v; u[row0 + 1] = u1v;
      atomicAdd(&eA[2], u0v * ss0 + u1v * ss1);   // loss partial
    }
  }
  gbar(cnt, phs);

  // ---- Phase C: t = colsum(E^T u1) (kept in regs), err1 --------------------
  float tt = 0.f;
  {
    if (tid < NROW) sU[tid] = u[tid];
    __syncthreads();
    const float* Mp = M + (size_t)r0 * NCOL + col0;
    float4 cs = {0.f, 0.f, 0.f, 0.f};
    #pragma unroll 8
    for (int rr = 0; rr < 32; ++rr) {
      float4 m = *(const float4*)(Mp + (size_t)rr * NCOL);
      float us = sU[r0 + rr];
      cs.x = fmaf(__expf(-20.f * m.x), us, cs.x);
      cs.y = fmaf(__expf(-20.f * m.y), us, cs.y);
      cs.z = fmaf(__expf(-20.f * m.z), us, cs.z);
      cs.w = fmaf(__expf(-20.f * m.w), us, cs.w);
    }
    *(float4*)(sCol + part * 256 + (chunk << 2)) = cs;
    __syncthreads();
    float pe = 0.f;
    if (tid < 256) {
      #pragma unroll
      for (int p = 0; p < 16; ++p) tt += sCol[p * 256 + tid];
      pe = fabsf(v[(bid << 8) + tid] * tt - bm);
    }
    pe = wave_sum(pe);
    if ((tid & 63) == 0) sRedA[tid >> 6] = pe;
    __syncthreads();
    if (tid == 0) {
      float s = 0.f;
      #pragma unroll
      for (int w = 0; w < 16; ++w) s += sRedA[w];
      atomicAdd(&eA[0], s);
    }
  }
  gbar(cnt, phs);

  // ---- decide --------------------------------------------------------------
  if (tid == 0) { sDecE = atomicAdd(&eA[0], 0.f); sDecL = atomicAdd(&eA[2], 0.f); }
  __syncthreads();
  if (sDecE <= 0.005f) {
    if (bid == 0 && tid == 0) out[0] = 100.f * sDecL;
    return;
  }

  // ---- fallback: iters 2..100 (tt live in regs) ----------------------------
  if (bid == 0 && tid == 0) out[0] = 0.f;
  int cpt = 1;
  while (true) {
    if (tid < 256) v[(bid << 8) + tid] = bm / (tt + EPSV);
    gbar(cnt, phs);
    cpt++;
    {
      const float4* M40 = (const float4*)M + (size_t)row0 * (NCOL / 4);
      const float4* M41 = M40 + (NCOL / 4);
      const float4* V4  = (const float4*)v;
      float ra = 0.f, rb = 0.f;
      #pragma unroll 4
      for (int it = 0; it < NCOL / 4 / 1024; ++it) {
        const int c = (it << 10) + tid;
        float4 vv = V4[c];
        float4 m0 = M40[c], m1 = M41[c];
        ra += __expf(-20.f * m0.x) * vv.x + __expf(-20.f * m0.y) * vv.y
            + __expf(-20.f * m0.z) * vv.z + __expf(-20.f * m0.w) * vv.w;
        rb += __expf(-20.f * m1.x) * vv.x + __expf(-20.f * m1.y) * vv.y
            + __expf(-20.f * m1.z) * vv.z + __expf(-20.f * m1.w) * vv.w;
      }
      ra = wave_sum(ra); rb = wave_sum(rb);
      if ((tid & 63) == 0) { sRedA[tid >> 6] = ra; sRedB[tid >> 6] = rb; }
      __syncthreads();
      if (tid < 2) {
        const float* sr = (tid == 0) ? sRedA : sRedB;
        float s = 0.f;
        #pragma unroll
        for (int w = 0; w < 16; ++w) s += sr[w];
        u[row0 + tid] = am / (s + EPSV);
      }
    }
    gbar(cnt, phs);
    if (cpt >= 100) break;

    if (tid < NROW) sU[tid] = u[tid];
    __syncthreads();
    float4 cs = {0.f, 0.f, 0.f, 0.f};
    #pragma unroll 4
    for (int r = r0; r < r0 + 32; ++r) {
      float4 m = *(const float4*)(M + (size_t)r * NCOL + col0);
      float us = sU[r];
      cs.x = fmaf(__expf(-20.f * m.x), us, cs.x);
      cs.y = fmaf(__expf(-20.f * m.y), us, cs.y);
      cs.z = fmaf(__expf(-20.f * m.z), us, cs.z);
      cs.w = fmaf(__expf(-20.f * m.w), us, cs.w);
    }
    *(float4*)(sCol + part * 256 + (chunk << 2)) = cs;
    __syncthreads();
    if (tid < 256) {
      tt = 0.f;
      #pragma unroll
      for (int p = 0; p < 16; ++p) tt += sCol[p * 256 + tid];
    }

    if (cpt == 51) {
      float pe = (tid < 256) ? fabsf(v[(bid << 8) + tid] * tt - bm) : 0.f;
      pe = wave_sum(pe);
      __syncthreads();
      if ((tid & 63) == 0) sRedA[tid >> 6] = pe;
      __syncthreads();
      if (tid == 0) {
        float s = 0.f;
        #pragma unroll
        for (int w = 0; w < 16; ++w) s += sRedA[w];
        atomicAdd(&eA[1], s);
      }
      gbar(cnt, phs);
      if (tid == 0) sDecE = atomicAdd(&eA[1], 0.f);
      __syncthreads();
      if (sDecE <= 0.005f) break;
    }
  }

  // final loss with current u, v
  __syncthreads();
  if (tid < NROW) sU[tid] = u[tid];
  __syncthreads();
  {
    const float4 vv = *(const float4*)(v + col0);
    const float* Mp = M + (size_t)r0 * NCOL + col0;
    float lacc = 0.f;
    #pragma unroll 4
    for (int rr = 0; rr < 32; ++rr) {
      float4 m = *(const float4*)(Mp + (size_t)rr * NCOL);
      float us = sU[r0 + rr];
      lacc += us * (__expf(-20.f * m.x) * m.x * vv.x
                  + __expf(-20.f * m.y) * m.y * vv.y
                  + __expf(-20.f * m.z) * m.z * vv.z
                  + __expf(-20.f * m.w) * m.w * vv.w);
    }
    lacc = wave_sum(lacc);
    if ((tid & 63) == 0) sRedA[tid >> 6] = lacc;
    __syncthreads();
    if (tid == 0) {
      float s = 0.f;
      #pragma unroll
      for (int w = 0; w < 16; ++w) s += sRedA[w];
      atomicAdd(out, 100.f * s);
    }
  }
}

extern "C" void kernel_launch(void* const* d_in, const int* in_sizes, int n_in,
                              void* d_out, int out_size, void* d_ws, size_t ws_size,
                              hipStream_t stream) {
  const float* M = (const float*)d_in[0];
  float* out = (float*)d_out;

  // ws: v (256 KB) | u (4 KB pad) | eA | bar
  const size_t offV = 0;
  const size_t offU = offV + (size_t)NCOL * sizeof(float);
  const size_t offE = offU + 4096;
  const size_t offB = offE + 256;
  const size_t need = offB + 256;
  if (ws_size < need) return;

  char* ws = (char*)d_ws;
  float* v  = (float*)(ws + offV);
  float* u  = (float*)(ws + offU);
  float* eA = (float*)(ws + offE);
  int*   bar = (int*)(ws + offB);

  init_ws<<<dim3(1), dim3(64), 0, stream>>>(eA, bar);
  sinkhorn_all<<<dim3(256), dim3(1024), 0, stream>>>(M, out, v, u, eA, bar);
}

// Round 10
// 243.330 us; speedup vs baseline: 1.2246x; 1.2246x over previous
//
#include <hip/hip_runtime.h>

#define NROW 512
#define NCOL 65536

static __device__ __forceinline__ float wave_sum(float x) {
  #pragma unroll
  for (int off = 32; off; off >>= 1) x += __shfl_down(x, off, 64);
  return x;
}

// Device-scope grid barrier (monotone phase counter). 256 blocks co-resident.
static __device__ __forceinline__ void gbar(int* cnt, int* phase) {
  __syncthreads();
  if (threadIdx.x == 0) {
    int ph = atomicAdd(phase, 0);
    __threadfence();
    if (atomicAdd(cnt, 1) == (int)gridDim.x - 1) {
      atomicExch(cnt, 0);
      __threadfence();
      atomicAdd(phase, 1);
    } else {
      while (atomicAdd(phase, 0) == ph) { __builtin_amdgcn_s_sleep(8); }
    }
    __threadfence();
  }
  __syncthreads();
}

// ---- k1a: banded partial colsums of E; 1024 blocks x 512 thr (4 blk/CU) ----
// Block (band, colblk): rows [band*256,+256), cols [colblk*128,+128).
// Thread: 4 cols x 16 rows.
__global__ __launch_bounds__(512)
void k1a_colsum(const float* __restrict__ M, float* __restrict__ tPart,
                float* __restrict__ eA, int* __restrict__ bar) {
  const int tid = threadIdx.x, bid = blockIdx.x;
  const int colblk = bid & 511, band = bid >> 9;
  const int chunk = tid & 31;           // 32 chunks x 4 cols = 128 cols
  const int part  = tid >> 5;           // 16 parts x 16 rows = 256 rows
  const int col0  = (colblk << 7) + (chunk << 2);
  const int r0    = (band << 8) + (part << 4);

  __shared__ float sCol[16 * 128];

  if (bid == 0 && tid < 8) eA[tid] = 0.f;  // [0]=err1 [1]=err51 [2]=loss [4]=cnt
  if (bid == 0 && tid < 2) bar[tid] = 0;   // k5 barrier cnt/phase

  const float* Mp = M + (size_t)r0 * NCOL + col0;
  float4 cs = {0.f, 0.f, 0.f, 0.f};
  #pragma unroll 8
  for (int rr = 0; rr < 16; ++rr) {
    float4 m = *(const float4*)(Mp + (size_t)rr * NCOL);
    cs.x += __expf(-20.f * m.x);
    cs.y += __expf(-20.f * m.y);
    cs.z += __expf(-20.f * m.z);
    cs.w += __expf(-20.f * m.w);
  }
  *(float4*)(sCol + part * 128 + (chunk << 2)) = cs;
  __syncthreads();
  if (tid < 128) {
    float t = 0.f;
    #pragma unroll
    for (int p = 0; p < 16; ++p) t += sCol[p * 128 + tid];
    tPart[(size_t)band * NCOL + (colblk << 7) + tid] = t;
  }
}

// ---- k1b: v1 = b / ((band0+band1)/512 + eps) -------------------------------
__global__ __launch_bounds__(256)
void k1b_v1(const float* __restrict__ tPart, float* __restrict__ v) {
  const int gid = blockIdx.x * 256 + threadIdx.x;
  const int col0 = gid << 2;
  const float am = 1.0f / NROW, bm = 1.0f / NCOL, EPSV = 1e-16f;
  float4 p0 = *(const float4*)(tPart + col0);
  float4 p1 = *(const float4*)(tPart + NCOL + col0);
  float4 vv = {bm / ((p0.x + p1.x) * am + EPSV),
               bm / ((p0.y + p1.y) * am + EPSV),
               bm / ((p0.z + p1.z) * am + EPSV),
               bm / ((p0.w + p1.w) * am + EPSV)};
  *(float4*)(v + col0) = vv;
}

// ---- k2: u1[row] = a/(E[row,:].v+eps); 512 blocks x 1024 thr (2 blk/CU) ----
__global__ __launch_bounds__(1024)
void k2_rowdot(const float* __restrict__ M, const float* __restrict__ v,
               float* __restrict__ u) {
  const int tid = threadIdx.x, row = blockIdx.x;
  const float am = 1.0f / NROW, EPSV = 1e-16f;
  const float4* M4 = (const float4*)M + (size_t)row * (NCOL / 4);
  const float4* V4 = (const float4*)v;
  __shared__ float sRed[16];

  float acc = 0.f;
  #pragma unroll 4
  for (int it = 0; it < NCOL / 4 / 1024; ++it) {   // 16 iters
    const int c = (it << 10) + tid;
    float4 m = M4[c];
    float4 vv = V4[c];
    acc += __expf(-20.f * m.x) * vv.x + __expf(-20.f * m.y) * vv.y
         + __expf(-20.f * m.z) * vv.z + __expf(-20.f * m.w) * vv.w;
  }
  acc = wave_sum(acc);
  if ((tid & 63) == 0) sRed[tid >> 6] = acc;
  __syncthreads();
  if (tid == 0) {
    float s = 0.f;
    #pragma unroll
    for (int w = 0; w < 16; ++w) s += sRed[w];
    u[row] = am / (s + EPSV);
  }
}

// ---- k3a: banded partial colsums of E^T u1 + fused loss partial ------------
// Same geometry as k1a.
__global__ __launch_bounds__(512)
void k3a_colsum_u(const float* __restrict__ M, const float* __restrict__ v,
                  const float* __restrict__ u, float* __restrict__ tPart,
                  float* __restrict__ eA) {
  const int tid = threadIdx.x, bid = blockIdx.x;
  const int colblk = bid & 511, band = bid >> 9;
  const int chunk = tid & 31;
  const int part  = tid >> 5;
  const int col0  = (colblk << 7) + (chunk << 2);
  const int r0l   = part << 4;              // local row in band

  __shared__ float sU[256];
  __shared__ float sCol[16 * 128];
  __shared__ float sRed[8];

  if (tid < 256) sU[tid] = u[(band << 8) + tid];
  __syncthreads();

  const float4 vv = *(const float4*)(v + col0);
  const float* Mp = M + (size_t)((band << 8) + r0l) * NCOL + col0;
  float4 cs = {0.f, 0.f, 0.f, 0.f};
  float lacc = 0.f;
  #pragma unroll 8
  for (int rr = 0; rr < 16; ++rr) {
    float4 m = *(const float4*)(Mp + (size_t)rr * NCOL);
    float e0 = __expf(-20.f * m.x), e1 = __expf(-20.f * m.y);
    float e2 = __expf(-20.f * m.z), e3 = __expf(-20.f * m.w);
    float us = sU[r0l + rr];
    cs.x = fmaf(e0, us, cs.x);
    cs.y = fmaf(e1, us, cs.y);
    cs.z = fmaf(e2, us, cs.z);
    cs.w = fmaf(e3, us, cs.w);
    lacc += us * (e0 * m.x * vv.x + e1 * m.y * vv.y
                + e2 * m.z * vv.z + e3 * m.w * vv.w);
  }
  *(float4*)(sCol + part * 128 + (chunk << 2)) = cs;
  lacc = wave_sum(lacc);
  if ((tid & 63) == 0) sRed[tid >> 6] = lacc;
  __syncthreads();
  if (tid < 128) {
    float t = 0.f;
    #pragma unroll
    for (int p = 0; p < 16; ++p) t += sCol[p * 128 + tid];
    tPart[(size_t)band * NCOL + (colblk << 7) + tid] = t;
  }
  if (tid == 0)
    atomicAdd(&eA[2], sRed[0] + sRed[1] + sRed[2] + sRed[3]
                    + sRed[4] + sRed[5] + sRed[6] + sRed[7]);
}

// ---- k3b: t = band0+band1, tArr, err1, + last-block decide -----------------
__global__ __launch_bounds__(256)
void k3b_err(const float* __restrict__ tPart, const float* __restrict__ v,
             float* __restrict__ tArr, float* __restrict__ eA,
             float* __restrict__ out, int* __restrict__ done) {
  const int tid = threadIdx.x;
  const int gid = blockIdx.x * 256 + tid;
  const int col0 = gid << 2;
  const float bm = 1.0f / NCOL;
  __shared__ float sRed[4];

  float4 p0 = *(const float4*)(tPart + col0);
  float4 p1 = *(const float4*)(tPart + NCOL + col0);
  float4 t = {p0.x + p1.x, p0.y + p1.y, p0.z + p1.z, p0.w + p1.w};
  *(float4*)(tArr + col0) = t;
  float4 vv = *(const float4*)(v + col0);
  float pe = fabsf(vv.x * t.x - bm) + fabsf(vv.y * t.y - bm)
           + fabsf(vv.z * t.z - bm) + fabsf(vv.w * t.w - bm);
  pe = wave_sum(pe);
  if ((tid & 63) == 0) sRed[tid >> 6] = pe;
  __syncthreads();
  if (tid == 0) {
    atomicAdd(&eA[0], sRed[0] + sRed[1] + sRed[2] + sRed[3]);
    __threadfence();
    int old = atomicAdd((int*)(eA + 4), 1);
    if (old == (int)gridDim.x - 1) {
      __threadfence();
      float err = atomicAdd(&eA[0], 0.f);
      float ls  = atomicAdd(&eA[2], 0.f);
      if (err <= 0.005f) { out[0] = 100.f * ls; done[0] = 1; }
      else               { out[0] = 0.f;        done[0] = 0; }
    }
  }
}

// ---- k5: persistent fallback, normal launch + gbar (R6-proven) -------------
__global__ __launch_bounds__(1024)
void k5_fallback(const float* __restrict__ M, float* __restrict__ out,
                 float* __restrict__ v, float* __restrict__ u,
                 const float* __restrict__ tArr, float* __restrict__ eA,
                 const int* __restrict__ done, int* __restrict__ bar) {
  if (done[0]) return;
  const int tid = threadIdx.x, bid = blockIdx.x;
  const float am = 1.0f / NROW, bm = 1.0f / NCOL, EPSV = 1e-16f;
  int* cnt = bar;
  int* phs = bar + 1;

  __shared__ float sU[NROW];
  __shared__ float sCol[16 * 256];
  __shared__ float sRedA[16], sRedB[16];
  __shared__ float sErr;

  const int chunk = tid & 63;
  const int part  = tid >> 6;
  const int col0  = (bid << 8) + (chunk << 2);
  const int r0    = part << 5;
  const int row0  = bid << 1;

  float tt = (tid < 256) ? tArr[(bid << 8) + tid] : 0.f;

  int cpt = 1;
  while (true) {
    if (tid < 256) v[(bid << 8) + tid] = bm / (tt + EPSV);
    gbar(cnt, phs);
    cpt++;

    {
      const float4* M40 = (const float4*)M + (size_t)row0 * (NCOL / 4);
      const float4* M41 = (const float4*)M + (size_t)(row0 + 1) * (NCOL / 4);
      const float4* V4  = (const float4*)v;
      float ra = 0.f, rb = 0.f;
      #pragma unroll 4
      for (int it = 0; it < NCOL / 4 / 1024; ++it) {
        const int c = (it << 10) + tid;
        float4 vv = V4[c];
        float4 m0 = M40[c], m1 = M41[c];
        ra += __expf(-20.f * m0.x) * vv.x + __expf(-20.f * m0.y) * vv.y
            + __expf(-20.f * m0.z) * vv.z + __expf(-20.f * m0.w) * vv.w;
        rb += __expf(-20.f * m1.x) * vv.x + __expf(-20.f * m1.y) * vv.y
            + __expf(-20.f * m1.z) * vv.z + __expf(-20.f * m1.w) * vv.w;
      }
      ra = wave_sum(ra); rb = wave_sum(rb);
      if ((tid & 63) == 0) { sRedA[tid >> 6] = ra; sRedB[tid >> 6] = rb; }
      __syncthreads();
      if (tid < 2) {
        const float* sr = (tid == 0) ? sRedA : sRedB;
        float s = 0.f;
        #pragma unroll
        for (int w = 0; w < 16; ++w) s += sr[w];
        u[row0 + tid] = am / (s + EPSV);
      }
    }
    gbar(cnt, phs);
    if (cpt >= 100) break;

    if (tid < NROW) sU[tid] = u[tid];
    __syncthreads();
    float4 cs = {0.f, 0.f, 0.f, 0.f};
    #pragma unroll 4
    for (int r = r0; r < r0 + 32; ++r) {
      float4 m = *(const float4*)(M + (size_t)r * NCOL + col0);
      float us = sU[r];
      cs.x = fmaf(__expf(-20.f * m.x), us, cs.x);
      cs.y = fmaf(__expf(-20.f * m.y), us, cs.y);
      cs.z = fmaf(__expf(-20.f * m.z), us, cs.z);
      cs.w = fmaf(__expf(-20.f * m.w), us, cs.w);
    }
    *(float4*)(sCol + part * 256 + (chunk << 2)) = cs;
    __syncthreads();
    if (tid < 256) {
      tt = 0.f;
      #pragma unroll
      for (int p = 0; p < 16; ++p) tt += sCol[p * 256 + tid];
    }

    if (cpt == 51) {
      float pe = (tid < 256) ? fabsf(v[(bid << 8) + tid] * tt - bm) : 0.f;
      pe = wave_sum(pe);
      __syncthreads();
      if ((tid & 63) == 0) sRedA[tid >> 6] = pe;
      __syncthreads();
      if (tid == 0) {
        float s = 0.f;
        #pragma unroll
        for (int w = 0; w < 16; ++w) s += sRedA[w];
        atomicAdd(&eA[1], s);
      }
      gbar(cnt, phs);
      if (tid == 0) sErr = atomicAdd(&eA[1], 0.f);
      __syncthreads();
      if (sErr <= 0.005f) break;
    }
  }

  __syncthreads();
  if (tid < NROW) sU[tid] = u[tid];
  __syncthreads();
  {
    const float4 vv = *(const float4*)(v + col0);
    float lacc = 0.f;
    #pragma unroll 4
    for (int r = r0; r < r0 + 32; ++r) {
      float4 m = *(const float4*)(M + (size_t)r * NCOL + col0);
      float us = sU[r];
      lacc += us * (__expf(-20.f * m.x) * m.x * vv.x
                  + __expf(-20.f * m.y) * m.y * vv.y
                  + __expf(-20.f * m.z) * m.z * vv.z
                  + __expf(-20.f * m.w) * m.w * vv.w);
    }
    lacc = wave_sum(lacc);
    if ((tid & 63) == 0) sRedA[tid >> 6] = lacc;
    __syncthreads();
    if (tid == 0) {
      float s = 0.f;
      #pragma unroll
      for (int w = 0; w < 16; ++w) s += sRedA[w];
      atomicAdd(out, 100.f * s);
    }
  }
}

extern "C" void kernel_launch(void* const* d_in, const int* in_sizes, int n_in,
                              void* d_out, int out_size, void* d_ws, size_t ws_size,
                              hipStream_t stream) {
  const float* M = (const float*)d_in[0];
  float* out = (float*)d_out;

  // ws: v | tArr | u | eA(+cnt) | done | bar | tPart(2 bands)
  const size_t offV = 0;
  const size_t offT = offV + (size_t)NCOL * sizeof(float);      // 256 KB
  const size_t offU = offT + (size_t)NCOL * sizeof(float);      // 256 KB
  const size_t offE = offU + 4096;
  const size_t offD = offE + 256;
  const size_t offB = offD + 256;
  const size_t offP = offB + 256;
  const size_t need = offP + 2 * (size_t)NCOL * sizeof(float);  // +512 KB
  if (ws_size < need) return;

  char* ws = (char*)d_ws;
  float* v     = (float*)(ws + offV);
  float* tArr  = (float*)(ws + offT);
  float* u     = (float*)(ws + offU);
  float* eA    = (float*)(ws + offE);
  int*   done  = (int*)(ws + offD);
  int*   bar   = (int*)(ws + offB);
  float* tPart = (float*)(ws + offP);

  k1a_colsum  <<<dim3(1024), dim3(512),  0, stream>>>(M, tPart, eA, bar);
  k1b_v1      <<<dim3(64),   dim3(256),  0, stream>>>(tPart, v);
  k2_rowdot   <<<dim3(512),  dim3(1024), 0, stream>>>(M, v, u);
  k3a_colsum_u<<<dim3(1024), dim3(512),  0, stream>>>(M, v, u, tPart, eA);
  k3b_err     <<<dim3(64),   dim3(256),  0, stream>>>(tPart, v, tArr, eA, out, done);
  k5_fallback <<<dim3(256),  dim3(1024), 0, stream>>>(M, out, v, u, tArr, eA,
                                                      done, bar);
}

// Round 11
// 242.183 us; speedup vs baseline: 1.2304x; 1.0047x over previous
//
#include <hip/hip_runtime.h>

#define NROW 512
#define NCOL 65536
#define BANDS 4   // 4 row-bands of 128 rows for k1a/k3a

static __device__ __forceinline__ float wave_sum(float x) {
  #pragma unroll
  for (int off = 32; off; off >>= 1) x += __shfl_down(x, off, 64);
  return x;
}

// Device-scope grid barrier (monotone phase counter). 256 blocks co-resident.
static __device__ __forceinline__ void gbar(int* cnt, int* phase) {
  __syncthreads();
  if (threadIdx.x == 0) {
    int ph = atomicAdd(phase, 0);
    __threadfence();
    if (atomicAdd(cnt, 1) == (int)gridDim.x - 1) {
      atomicExch(cnt, 0);
      __threadfence();
      atomicAdd(phase, 1);
    } else {
      while (atomicAdd(phase, 0) == ph) { __builtin_amdgcn_s_sleep(8); }
    }
    __threadfence();
  }
  __syncthreads();
}

static __device__ __forceinline__ unsigned short f2bf(float f) {
  unsigned int u = __float_as_uint(f);
  u += 0x7FFFu + ((u >> 16) & 1u);       // round-to-nearest-even
  return (unsigned short)(u >> 16);
}
static __device__ __forceinline__ float bf2f_lo(unsigned int w) {
  return __uint_as_float(w << 16);
}
static __device__ __forceinline__ float bf2f_hi(unsigned int w) {
  return __uint_as_float(w & 0xFFFF0000u);
}

// ---- k1a: partial colsums of E = exp(-20M); writes E16 cache ---------------
// 1024 blocks x 512 thr (4 blk/CU, 32 waves/CU). Block (band, colblk):
// rows [band*128,+128), cols [colblk*256,+256). Thread: 4 cols x 16 rows.
// Wave reads 1 KB contiguous per row-visit; writes 512 B of bf16 E.
__global__ __launch_bounds__(512)
void k1a_colsum(const float* __restrict__ M, unsigned short* __restrict__ E16,
                float* __restrict__ tPart, float* __restrict__ eA,
                int* __restrict__ bar) {
  const int tid = threadIdx.x, bid = blockIdx.x;
  const int colblk = bid & 255, band = bid >> 8;
  const int chunk = tid & 63;           // 64 chunks x 4 cols = 256 cols
  const int part  = tid >> 6;           // 8 parts x 16 rows = 128 rows
  const int col0  = (colblk << 8) + (chunk << 2);
  const int r0    = (band << 7) + (part << 4);

  __shared__ float sCol[8 * 256];

  if (bid == 0 && tid < 8) eA[tid] = 0.f;  // [0]=err1 [1]=err51 [2]=loss [4]=cnt
  if (bid == 0 && tid < 2) bar[tid] = 0;   // k5 barrier cnt/phase

  const float* Mp = M + (size_t)r0 * NCOL + col0;
  unsigned short* Ep = E16 + (size_t)r0 * NCOL + col0;
  float4 cs = {0.f, 0.f, 0.f, 0.f};
  #pragma unroll 8
  for (int rr = 0; rr < 16; ++rr) {
    float4 m = *(const float4*)(Mp + (size_t)rr * NCOL);
    float e0 = __expf(-20.f * m.x), e1 = __expf(-20.f * m.y);
    float e2 = __expf(-20.f * m.z), e3 = __expf(-20.f * m.w);
    cs.x += e0; cs.y += e1; cs.z += e2; cs.w += e3;
    uint2 w;
    w.x = (unsigned int)f2bf(e0) | ((unsigned int)f2bf(e1) << 16);
    w.y = (unsigned int)f2bf(e2) | ((unsigned int)f2bf(e3) << 16);
    *(uint2*)(Ep + (size_t)rr * NCOL) = w;
  }
  *(float4*)(sCol + part * 256 + (chunk << 2)) = cs;
  __syncthreads();
  if (tid < 256) {
    float t = 0.f;
    #pragma unroll
    for (int p = 0; p < 8; ++p) t += sCol[p * 256 + tid];
    tPart[(size_t)band * NCOL + (colblk << 8) + tid] = t;
  }
}

// ---- k1b: v1 = b / (colsum/512 + eps) --------------------------------------
__global__ __launch_bounds__(256)
void k1b_v1(const float* __restrict__ tPart, float* __restrict__ v) {
  const int gid = blockIdx.x * 256 + threadIdx.x;
  const int col0 = gid << 2;
  const float am = 1.0f / NROW, bm = 1.0f / NCOL, EPSV = 1e-16f;
  float4 t = {0.f, 0.f, 0.f, 0.f};
  #pragma unroll
  for (int b = 0; b < BANDS; ++b) {
    float4 p = *(const float4*)(tPart + (size_t)b * NCOL + col0);
    t.x += p.x; t.y += p.y; t.z += p.z; t.w += p.w;
  }
  float4 vv = {bm / (t.x * am + EPSV), bm / (t.y * am + EPSV),
               bm / (t.z * am + EPSV), bm / (t.w * am + EPSV)};
  *(float4*)(v + col0) = vv;
}

// ---- k2: u1[row] = a/(E[row,:].v+eps) reading bf16 E -----------------------
// 512 blocks x 1024 thr (2 blk/CU, 32 waves/CU); 8 cols/thread via uint4.
__global__ __launch_bounds__(1024)
void k2_rowdot(const unsigned short* __restrict__ E16,
               const float* __restrict__ v, float* __restrict__ u) {
  const int tid = threadIdx.x, row = blockIdx.x;
  const float am = 1.0f / NROW, EPSV = 1e-16f;
  const uint4* E4 = (const uint4*)(E16 + (size_t)row * NCOL);
  const float4* V4 = (const float4*)v;
  __shared__ float sRed[16];

  float acc = 0.f;
  #pragma unroll 4
  for (int it = 0; it < NCOL / 8 / 1024; ++it) {   // 8 iters
    const int c = (it << 10) + tid;
    uint4 w = E4[c];
    float4 va = V4[2 * c], vb = V4[2 * c + 1];
    acc += bf2f_lo(w.x) * va.x + bf2f_hi(w.x) * va.y
         + bf2f_lo(w.y) * va.z + bf2f_hi(w.y) * va.w
         + bf2f_lo(w.z) * vb.x + bf2f_hi(w.z) * vb.y
         + bf2f_lo(w.w) * vb.z + bf2f_hi(w.w) * vb.w;
  }
  acc = wave_sum(acc);
  if ((tid & 63) == 0) sRed[tid >> 6] = acc;
  __syncthreads();
  if (tid == 0) {
    float s = 0.f;
    #pragma unroll
    for (int w = 0; w < 16; ++w) s += sRed[w];
    u[row] = am / (s + EPSV);
  }
}

// ---- k3a: partial colsums of E^T u1 + loss from log-reconstructed M --------
// Same geometry as k1a; reads bf16 E only. M' = -ln(E)/20.
__global__ __launch_bounds__(512)
void k3a_colsum_u(const unsigned short* __restrict__ E16,
                  const float* __restrict__ v, const float* __restrict__ u,
                  float* __restrict__ tPart, float* __restrict__ eA) {
  const int tid = threadIdx.x, bid = blockIdx.x;
  const int colblk = bid & 255, band = bid >> 8;
  const int chunk = tid & 63;
  const int part  = tid >> 6;
  const int col0  = (colblk << 8) + (chunk << 2);
  const int r0l   = part << 4;              // local row in band

  __shared__ float sU[128];
  __shared__ float sCol[8 * 256];
  __shared__ float sRed[8];

  if (tid < 128) sU[tid] = u[(band << 7) + tid];
  __syncthreads();

  const float4 vv = *(const float4*)(v + col0);
  const unsigned short* Ep = E16 + (size_t)((band << 7) + r0l) * NCOL + col0;
  float4 cs = {0.f, 0.f, 0.f, 0.f};
  float lacc = 0.f;
  #pragma unroll 8
  for (int rr = 0; rr < 16; ++rr) {
    uint2 w = *(const uint2*)(Ep + (size_t)rr * NCOL);
    float e0 = bf2f_lo(w.x), e1 = bf2f_hi(w.x);
    float e2 = bf2f_lo(w.y), e3 = bf2f_hi(w.y);
    float us = sU[r0l + rr];
    cs.x = fmaf(e0, us, cs.x);
    cs.y = fmaf(e1, us, cs.y);
    cs.z = fmaf(e2, us, cs.z);
    cs.w = fmaf(e3, us, cs.w);
    float m0 = __logf(e0) * (-0.05f);
    float m1 = __logf(e1) * (-0.05f);
    float m2 = __logf(e2) * (-0.05f);
    float m3 = __logf(e3) * (-0.05f);
    lacc += us * (e0 * m0 * vv.x + e1 * m1 * vv.y
                + e2 * m2 * vv.z + e3 * m3 * vv.w);
  }
  *(float4*)(sCol + part * 256 + (chunk << 2)) = cs;
  lacc = wave_sum(lacc);
  if ((tid & 63) == 0) sRed[tid >> 6] = lacc;
  __syncthreads();
  if (tid < 256) {
    float t = 0.f;
    #pragma unroll
    for (int p = 0; p < 8; ++p) t += sCol[p * 256 + tid];
    tPart[(size_t)band * NCOL + (colblk << 8) + tid] = t;
  }
  if (tid == 0)
    atomicAdd(&eA[2], sRed[0] + sRed[1] + sRed[2] + sRed[3]
                    + sRed[4] + sRed[5] + sRed[6] + sRed[7]);
}

// ---- k3b: t = sum(bands), tArr, err1, + last-block decide ------------------
__global__ __launch_bounds__(256)
void k3b_err(const float* __restrict__ tPart, const float* __restrict__ v,
             float* __restrict__ tArr, float* __restrict__ eA,
             float* __restrict__ out, int* __restrict__ done) {
  const int tid = threadIdx.x;
  const int gid = blockIdx.x * 256 + tid;
  const int col0 = gid << 2;
  const float bm = 1.0f / NCOL;
  __shared__ float sRed[4];

  float4 t = {0.f, 0.f, 0.f, 0.f};
  #pragma unroll
  for (int b = 0; b < BANDS; ++b) {
    float4 p = *(const float4*)(tPart + (size_t)b * NCOL + col0);
    t.x += p.x; t.y += p.y; t.z += p.z; t.w += p.w;
  }
  *(float4*)(tArr + col0) = t;
  float4 vv = *(const float4*)(v + col0);
  float pe = fabsf(vv.x * t.x - bm) + fabsf(vv.y * t.y - bm)
           + fabsf(vv.z * t.z - bm) + fabsf(vv.w * t.w - bm);
  pe = wave_sum(pe);
  if ((tid & 63) == 0) sRed[tid >> 6] = pe;
  __syncthreads();
  if (tid == 0) {
    atomicAdd(&eA[0], sRed[0] + sRed[1] + sRed[2] + sRed[3]);
    __threadfence();
    int old = atomicAdd((int*)(eA + 4), 1);
    if (old == (int)gridDim.x - 1) {
      __threadfence();
      float err = atomicAdd(&eA[0], 0.f);
      float ls  = atomicAdd(&eA[2], 0.f);
      if (err <= 0.005f) { out[0] = 100.f * ls; done[0] = 1; }
      else               { out[0] = 0.f;        done[0] = 0; }
    }
  }
}

// ---- k5: persistent fallback (fp32 M path, R6/R10-proven); stub if done ----
__global__ __launch_bounds__(1024)
void k5_fallback(const float* __restrict__ M, float* __restrict__ out,
                 float* __restrict__ v, float* __restrict__ u,
                 const float* __restrict__ tArr, float* __restrict__ eA,
                 const int* __restrict__ done, int* __restrict__ bar) {
  if (done[0]) return;
  const int tid = threadIdx.x, bid = blockIdx.x;
  const float am = 1.0f / NROW, bm = 1.0f / NCOL, EPSV = 1e-16f;
  int* cnt = bar;
  int* phs = bar + 1;

  __shared__ float sU[NROW];
  __shared__ float sCol[16 * 256];
  __shared__ float sRedA[16], sRedB[16];
  __shared__ float sErr;

  const int chunk = tid & 63;
  const int part  = tid >> 6;
  const int col0  = (bid << 8) + (chunk << 2);
  const int r0    = part << 5;
  const int row0  = bid << 1;

  float tt = (tid < 256) ? tArr[(bid << 8) + tid] : 0.f;

  int cpt = 1;
  while (true) {
    if (tid < 256) v[(bid << 8) + tid] = bm / (tt + EPSV);
    gbar(cnt, phs);
    cpt++;

    {
      const float4* M40 = (const float4*)M + (size_t)row0 * (NCOL / 4);
      const float4* M41 = (const float4*)M + (size_t)(row0 + 1) * (NCOL / 4);
      const float4* V4  = (const float4*)v;
      float ra = 0.f, rb = 0.f;
      #pragma unroll 4
      for (int it = 0; it < NCOL / 4 / 1024; ++it) {
        const int c = (it << 10) + tid;
        float4 vv = V4[c];
        float4 m0 = M40[c], m1 = M41[c];
        ra += __expf(-20.f * m0.x) * vv.x + __expf(-20.f * m0.y) * vv.y
            + __expf(-20.f * m0.z) * vv.z + __expf(-20.f * m0.w) * vv.w;
        rb += __expf(-20.f * m1.x) * vv.x + __expf(-20.f * m1.y) * vv.y
            + __expf(-20.f * m1.z) * vv.z + __expf(-20.f * m1.w) * vv.w;
      }
      ra = wave_sum(ra); rb = wave_sum(rb);
      if ((tid & 63) == 0) { sRedA[tid >> 6] = ra; sRedB[tid >> 6] = rb; }
      __syncthreads();
      if (tid < 2) {
        const float* sr = (tid == 0) ? sRedA : sRedB;
        float s = 0.f;
        #pragma unroll
        for (int w = 0; w < 16; ++w) s += sr[w];
        u[row0 + tid] = am / (s + EPSV);
      }
    }
    gbar(cnt, phs);
    if (cpt >= 100) break;

    if (tid < NROW) sU[tid] = u[tid];
    __syncthreads();
    float4 cs = {0.f, 0.f, 0.f, 0.f};
    #pragma unroll 4
    for (int r = r0; r < r0 + 32; ++r) {
      float4 m = *(const float4*)(M + (size_t)r * NCOL + col0);
      float us = sU[r];
      cs.x = fmaf(__expf(-20.f * m.x), us, cs.x);
      cs.y = fmaf(__expf(-20.f * m.y), us, cs.y);
      cs.z = fmaf(__expf(-20.f * m.z), us, cs.z);
      cs.w = fmaf(__expf(-20.f * m.w), us, cs.w);
    }
    *(float4*)(sCol + part * 256 + (chunk << 2)) = cs;
    __syncthreads();
    if (tid < 256) {
      tt = 0.f;
      #pragma unroll
      for (int p = 0; p < 16; ++p) tt += sCol[p * 256 + tid];
    }

    if (cpt == 51) {
      float pe = (tid < 256) ? fabsf(v[(bid << 8) + tid] * tt - bm) : 0.f;
      pe = wave_sum(pe);
      __syncthreads();
      if ((tid & 63) == 0) sRedA[tid >> 6] = pe;
      __syncthreads();
      if (tid == 0) {
        float s = 0.f;
        #pragma unroll
        for (int w = 0; w < 16; ++w) s += sRedA[w];
        atomicAdd(&eA[1], s);
      }
      gbar(cnt, phs);
      if (tid == 0) sErr = atomicAdd(&eA[1], 0.f);
      __syncthreads();
      if (sErr <= 0.005f) break;
    }
  }

  __syncthreads();
  if (tid < NROW) sU[tid] = u[tid];
  __syncthreads();
  {
    const float4 vv = *(const float4*)(v + col0);
    float lacc = 0.f;
    #pragma unroll 4
    for (int r = r0; r < r0 + 32; ++r) {
      float4 m = *(const float4*)(M + (size_t)r * NCOL + col0);
      float us = sU[r];
      lacc += us * (__expf(-20.f * m.x) * m.x * vv.x
                  + __expf(-20.f * m.y) * m.y * vv.y
                  + __expf(-20.f * m.z) * m.z * vv.z
                  + __expf(-20.f * m.w) * m.w * vv.w);
    }
    lacc = wave_sum(lacc);
    if ((tid & 63) == 0) sRedA[tid >> 6] = lacc;
    __syncthreads();
    if (tid == 0) {
      float s = 0.f;
      #pragma unroll
      for (int w = 0; w < 16; ++w) s += sRedA[w];
      atomicAdd(out, 100.f * s);
    }
  }
}

extern "C" void kernel_launch(void* const* d_in, const int* in_sizes, int n_in,
                              void* d_out, int out_size, void* d_ws, size_t ws_size,
                              hipStream_t stream) {
  const float* M = (const float*)d_in[0];
  float* out = (float*)d_out;

  // ws: v | tArr | u | eA(+cnt) | done | bar | tPart(4 bands) | E16 (64 MB)
  const size_t offV = 0;
  const size_t offT = offV + (size_t)NCOL * sizeof(float);       // 256 KB
  const size_t offU = offT + (size_t)NCOL * sizeof(float);       // 256 KB
  const size_t offE = offU + 4096;
  const size_t offD = offE + 256;
  const size_t offB = offD + 256;
  const size_t offP = offB + 256;
  const size_t offE16 = offP + (size_t)BANDS * NCOL * sizeof(float); // +1 MB
  const size_t need = offE16 + (size_t)NROW * NCOL * sizeof(unsigned short);
  if (ws_size < need) return;

  char* ws = (char*)d_ws;
  float* v     = (float*)(ws + offV);
  float* tArr  = (float*)(ws + offT);
  float* u     = (float*)(ws + offU);
  float* eA    = (float*)(ws + offE);
  int*   done  = (int*)(ws + offD);
  int*   bar   = (int*)(ws + offB);
  float* tPart = (float*)(ws + offP);
  unsigned short* E16 = (unsigned short*)(ws + offE16);

  k1a_colsum  <<<dim3(1024), dim3(512),  0, stream>>>(M, E16, tPart, eA, bar);
  k1b_v1      <<<dim3(64),   dim3(256),  0, stream>>>(tPart, v);
  k2_rowdot   <<<dim3(512),  dim3(1024), 0, stream>>>(E16, v, u);
  k3a_colsum_u<<<dim3(1024), dim3(512),  0, stream>>>(E16, v, u, tPart, eA);
  k3b_err     <<<dim3(64),   dim3(256),  0, stream>>>(tPart, v, tArr, eA, out, done);
  k5_fallback <<<dim3(256),  dim3(1024), 0, stream>>>(M, out, v, u, tArr, eA,
                                                      done, bar);
}